// Round 10
// baseline (301.541 us; speedup 1.0000x reference)
//
#include <hip/hip_runtime.h>
#include <hip/hip_bf16.h>
#include <math.h>

#define NODES 20000
#define EDGES 320000
#define NB 3
#define TOTN (NODES * NB)   // 60000
#define TOTE (EDGES * NB)   // 960000
#define D_IN 128
#define D_H 304
#define SCAN_B 59           // ceil(60000/1024)
#define SLICES 40
#define SLICE_E (EDGES / SLICES)   // 8000
#define SLICES_O 16
#define SLICE_EO (EDGES / SLICES_O) // 20000 (< 2^16, packed 16b safe)
#define ZX TOTN             // zero row index in X8 (row 60000)
#define ZQ (TOTN + 192)     // zero row index in Q8/P8 (row 60192, above GEMM ghost rows <=60159)
#define FILLB 120           // fill blocks in merged kernel
#define PACK1B 1875         // pack blocks (exact: 1920000/1024)
#define PREPW1B 240         // prepw blocks (exact: 245760/1024)

typedef __attribute__((ext_vector_type(4))) float f32x4;
typedef __attribute__((ext_vector_type(2))) float f32x2;

// async global->LDS, 16 B per lane; LDS dst must be wave-uniform base + lane*16
__device__ __forceinline__ void gload16(const void* g, void* l) {
    __builtin_amdgcn_global_load_lds(
        (const __attribute__((address_space(1))) unsigned*)g,
        (__attribute__((address_space(3))) unsigned*)l, 16, 0, 0);
}

// ------- per-(graph,slice) LDS histograms, packed 2 nodes/word (16b counts) -----
// in-degree: 120 slice-blocks (feeds O); out-degree: 48 coarse blocks (sum only).
__global__ __launch_bounds__(1024, 1) void k_hist(
    const int* __restrict__ s1, const int* __restrict__ d1,
    const int* __restrict__ s2, const int* __restrict__ d2,
    const int* __restrict__ s3, const int* __restrict__ d3,
    unsigned short* __restrict__ partial_in, unsigned short* __restrict__ partial_out,
    int* __restrict__ gctr) {
    __shared__ unsigned hist[NODES / 2];   // 40 KB
    if (blockIdx.x == 0 && blockIdx.y == 0 && threadIdx.x == 0) *gctr = 0;
    bool isOut = (blockIdx.y == 1);
    const int* ep;
    int ne;
    unsigned* po;
    if (isOut) {
        if (blockIdx.x >= NB * SLICES_O) return;   // 72 empty blocks, negligible
        int g = blockIdx.x / SLICES_O, s = blockIdx.x % SLICES_O;
        ep = ((g == 0) ? s1 : ((g == 1) ? s2 : s3)) + s * SLICE_EO;
        ne = SLICE_EO;
        po = (unsigned*)(partial_out + (size_t)blockIdx.x * NODES);
    } else {
        int g = blockIdx.x / SLICES, s = blockIdx.x % SLICES;
        ep = ((g == 0) ? d1 : ((g == 1) ? d2 : d3)) + s * SLICE_E;
        ne = SLICE_E;
        po = (unsigned*)(partial_in + (size_t)blockIdx.x * NODES);
    }
    for (int i = threadIdx.x; i < NODES / 2; i += 1024) hist[i] = 0;
    __syncthreads();
    const int4* ep4 = (const int4*)ep;
    for (int i = threadIdx.x; i < ne / 4; i += 1024) {
        int4 v = ep4[i];
        atomicAdd(&hist[v.x >> 1], 1u << ((v.x & 1) << 4));
        atomicAdd(&hist[v.y >> 1], 1u << ((v.y & 1) << 4));
        atomicAdd(&hist[v.z >> 1], 1u << ((v.z & 1) << 4));
        atomicAdd(&hist[v.w >> 1], 1u << ((v.w & 1) << 4));
    }
    __syncthreads();
    for (int i = threadIdx.x; i < NODES / 2; i += 1024) po[i] = hist[i];
}

// ------- degrees + inv factors + row_ptr (atomic block base) + O slice bases ---
// partial_in column register-cached (single pass feeds both ci sum and O bases).
__global__ void k_degscan(const unsigned short* __restrict__ partial_in,
                          const unsigned short* __restrict__ partial_out,
                          float* __restrict__ inv_in, float* __restrict__ inv_out,
                          int* __restrict__ row_ptr, int* __restrict__ rend,
                          int* __restrict__ O, int* __restrict__ gctr) {
    __shared__ int wsum[16];
    __shared__ int sbase;
    int b = blockIdx.x, t = threadIdx.x;
    int i = b * 1024 + t;
    int lane = t & 63, wid = t >> 6;
    int v = 0;
    int g = 0, ln = 0;
    int pc[SLICES];
    if (i < TOTN) {
        g = i / NODES; ln = i - g * NODES;
        const unsigned short* pi = partial_in + (size_t)g * SLICES * NODES + ln;
        const unsigned short* po = partial_out + (size_t)g * SLICES_O * NODES + ln;
        int ci = 0, co = 0;
        #pragma unroll
        for (int s = 0; s < SLICES; s++) { pc[s] = pi[s * NODES]; ci += pc[s]; }
        #pragma unroll
        for (int s = 0; s < SLICES_O; s++) co += po[s * NODES];
        v = ci;
        inv_in[i]  = 1.0f / sqrtf((float)max(ci, 1));
        inv_out[i] = 1.0f / sqrtf((float)max(co, 1));
    }
    int sv = v;
    #pragma unroll
    for (int o = 1; o < 64; o <<= 1) {
        int u = __shfl_up(sv, o, 64);
        if (lane >= o) sv += u;
    }
    if (lane == 63) wsum[wid] = sv;
    __syncthreads();
    if (t < 16) {
        int w = wsum[t];
        #pragma unroll
        for (int o = 1; o < 16; o <<= 1) {
            int u = __shfl_up(w, o, 16);
            if (t >= o) w += u;
        }
        wsum[t] = w;
    }
    __syncthreads();
    if (t == 0) sbase = atomicAdd(gctr, wsum[15]);
    __syncthreads();
    int wbase = (wid > 0) ? wsum[wid - 1] : 0;
    if (i < TOTN) {
        int rp = sbase + wbase + sv - v;
        row_ptr[i] = rp;
        rend[i] = rp + v;
        int* on = O + (size_t)g * SLICES * NODES + ln;
        int run = rp;
        #pragma unroll
        for (int s = 0; s < SLICES; s++) {
            on[s * NODES] = run;
            run += pc[s];
        }
    }
}

// ------- merged: CSR fill (LDS cursors) | pack x->fp8 | W prep | zero jobs -----
__global__ __launch_bounds__(1024, 1) void k_fillprep(
    const int* __restrict__ s1, const int* __restrict__ d1,
    const int* __restrict__ s2, const int* __restrict__ d2,
    const int* __restrict__ s3, const int* __restrict__ d3,
    const int* __restrict__ O, int* __restrict__ csr,
    const float4* __restrict__ x1, const float4* __restrict__ x2,
    const float4* __restrict__ x3, const float* __restrict__ inv_out,
    unsigned* __restrict__ q,
    const float* __restrict__ W1, const float* __restrict__ W2,
    const float* __restrict__ W3,
    unsigned char* __restrict__ Wt1, unsigned char* __restrict__ Wt2,
    unsigned char* __restrict__ Wt3,
    int* __restrict__ csr_slack, unsigned* __restrict__ x8z,
    unsigned* __restrict__ q8z, int* __restrict__ pooled, int* __restrict__ done) {
    __shared__ int cur[NODES];   // 80 KB (used by fill-role blocks only)
    int b = blockIdx.x;
    if (b < FILLB) {
        int g = b / SLICES, s = b % SLICES;
        const int* sp = (g == 0) ? s1 : ((g == 1) ? s2 : s3);
        const int* dp = (g == 0) ? d1 : ((g == 1) ? d2 : d3);
        sp += s * SLICE_E; dp += s * SLICE_E;
        const int* on = O + (size_t)b * NODES;
        for (int i = threadIdx.x; i < NODES; i += 1024) cur[i] = on[i];
        __syncthreads();
        int base = g * NODES;
        const int4* sp4 = (const int4*)sp;
        const int4* dp4 = (const int4*)dp;
        for (int i = threadIdx.x; i < SLICE_E / 4; i += 1024) {
            int4 dv = dp4[i];
            int4 sv = sp4[i];
            int p0 = atomicAdd(&cur[dv.x], 1); csr[p0] = sv.x + base;
            int p1 = atomicAdd(&cur[dv.y], 1); csr[p1] = sv.y + base;
            int p2 = atomicAdd(&cur[dv.z], 1); csr[p2] = sv.z + base;
            int p3 = atomicAdd(&cur[dv.w], 1); csr[p3] = sv.w + base;
        }
    } else if (b < FILLB + PACK1B) {
        const int per = NODES * D_IN / 4;  // float4s per graph (32 per row)
        int i = (b - FILLB) * 1024 + threadIdx.x;   // covers 3*per exactly
        const float4* s; int j;
        if (i < per)          { s = x1; j = i; }
        else if (i < 2 * per) { s = x2; j = i - per; }
        else                  { s = x3; j = i - 2 * per; }
        float4 v = s[j];
        float sc = inv_out[i >> 5];   // 32 dwords per row, global node id
        int p = __builtin_amdgcn_cvt_pk_fp8_f32(v.x * sc, v.y * sc, 0, false);
        p = __builtin_amdgcn_cvt_pk_fp8_f32(v.z * sc, v.w * sc, p, true);
        q[i] = (unsigned)p;
    } else if (b < FILLB + PACK1B + PREPW1B) {
        // Wt padded to 320 rows (rows 304-319 zero) for uniform GEMM B staging.
        const int N1 = 320 * 128, N2 = 320 * 320;
        int id = (b - FILLB - PACK1B) * 1024 + threadIdx.x;
        const float* W; unsigned char* Wt; int K, Kpad, lid;
        if (id < N1)                { W = W1; Wt = Wt1; K = 128; Kpad = 128; lid = id; }
        else if (id < N1 + N2)      { W = W2; Wt = Wt2; K = 304; Kpad = 320; lid = id - N1; }
        else                        { W = W3; Wt = Wt3; K = 304; Kpad = 320; lid = id - N1 - N2; }
        int n = lid / Kpad, k = lid - n * Kpad;
        unsigned char v = 0;
        if (k < K && n < D_H) {
            float w = W[k * D_H + n];
            v = (unsigned char)(__builtin_amdgcn_cvt_pk_fp8_f32(w, w, 0, false) & 0xff);
        }
        Wt[lid] = v;
    } else {
        int ex = threadIdx.x;
        if (ex < 32) csr_slack[ex] = 0;            // csr over-read slack
        else if (ex < 64) x8z[ex - 32] = 0;        // X8 zero row (128 B)
        else if (ex < 144) q8z[ex - 64] = 0;       // Q8 zero row (320 B)
        else if (ex < 464) pooled[ex - 144] = 0;   // pooled accumulator
        else if (ex == 464) done[0] = 0;           // gemm3 done-counter
    }
}

// ------- SpMM layer 1: straight-line predicated gather, 32 edges deep ---------
// (proven structure: 48 VGPR, no spill. One node/wave, 4 subgroups x 16 lanes)
__global__ void k_spmm_l1(const uint2* __restrict__ h, unsigned char* __restrict__ agg,
                          const int* __restrict__ row_ptr, const int* __restrict__ rend,
                          const int* __restrict__ csr,
                          const float* __restrict__ inv_in) {
    int n = blockIdx.x * 4 + (threadIdx.x >> 6);
    int lane = threadIdx.x & 63;
    int s = lane >> 4;          // edge subgroup 0..3
    int off = lane & 15;        // uint2 offset within row
    f32x2 a[4];
    #pragma unroll
    for (int j = 0; j < 4; j++) a[j] = (f32x2){0.f, 0.f};
    int k0 = row_ptr[n], k1 = rend[n];
    int deg = k1 - k0;
    const int* cp = csr + k0 + s;
    int e[8];
    #pragma unroll
    for (int j = 0; j < 8; j++) {
        int ev = cp[4 * j];                     // imm-offset load; slack-safe
        e[j] = (s + 4 * j < deg) ? ev : ZX;     // invalid -> zero row
    }
    uint2 u[8];
    #pragma unroll
    for (int j = 0; j < 8; j++)
        if (4 * j < deg) u[j] = h[(size_t)e[j] * 16 + off];   // wave-uniform skip
    #pragma unroll
    for (int j = 0; j < 8; j++) {
        if (4 * j < deg) {
            a[0] += __builtin_amdgcn_cvt_pk_f32_fp8(u[j].x, false);
            a[1] += __builtin_amdgcn_cvt_pk_f32_fp8(u[j].x, true);
            a[2] += __builtin_amdgcn_cvt_pk_f32_fp8(u[j].y, false);
            a[3] += __builtin_amdgcn_cvt_pk_f32_fp8(u[j].y, true);
        }
    }
    for (int k = k0 + 32 + s; k < k1; k += 4) {    // rare: degree > 32
        int e0 = csr[k];
        uint2 u0 = h[(size_t)e0 * 16 + off];
        a[0] += __builtin_amdgcn_cvt_pk_f32_fp8(u0.x, false);
        a[1] += __builtin_amdgcn_cvt_pk_f32_fp8(u0.x, true);
        a[2] += __builtin_amdgcn_cvt_pk_f32_fp8(u0.y, false);
        a[3] += __builtin_amdgcn_cvt_pk_f32_fp8(u0.y, true);
    }
    float r[8];
    #pragma unroll
    for (int j = 0; j < 4; j++) {
        #pragma unroll
        for (int c = 0; c < 2; c++) {
            float v = a[j][c];
            r[2 * j + c] = v + __shfl(v, lane + 16, 64)
                             + __shfl(v, lane + 32, 64)
                             + __shfl(v, lane + 48, 64);
        }
    }
    if (lane < 16) {
        float wi = inv_in[n];
        int d0 = __builtin_amdgcn_cvt_pk_fp8_f32(r[0] * wi, r[1] * wi, 0, false);
        d0 = __builtin_amdgcn_cvt_pk_fp8_f32(r[2] * wi, r[3] * wi, d0, true);
        int d1 = __builtin_amdgcn_cvt_pk_fp8_f32(r[4] * wi, r[5] * wi, 0, false);
        d1 = __builtin_amdgcn_cvt_pk_fp8_f32(r[6] * wi, r[7] * wi, d1, true);
        uint2 st; st.x = (unsigned)d0; st.y = (unsigned)d1;
        *(uint2*)(agg + (size_t)n * 128 + lane * 8) = st;
    }
}

// ------- SpMM layers 2/3: straight-line predicated gather, 24 edges deep ------
__global__ void k_spmm_big(const uint4* __restrict__ h, unsigned char* __restrict__ agg,
                           const int* __restrict__ row_ptr, const int* __restrict__ rend,
                           const int* __restrict__ csr,
                           const float* __restrict__ inv_in) {
    int n = blockIdx.x * 4 + (threadIdx.x >> 6);
    int lane = threadIdx.x & 63;
    int s = lane / 20;          // 0..2 (lanes 60-63: s=3, masked)
    int off = lane % 20;
    f32x2 a[8];
    #pragma unroll
    for (int j = 0; j < 8; j++) a[j] = (f32x2){0.f, 0.f};
    int k0 = row_ptr[n], k1 = rend[n];
    int deg = k1 - k0;
    int degg = (s < 3) ? deg : 0;         // s==3 lanes always invalid
    const int* cp = csr + k0 + s;
    int e[8];
    #pragma unroll
    for (int j = 0; j < 8; j++) {
        int ev = cp[3 * j];                     // imm-offset load; slack-safe
        e[j] = (s + 3 * j < degg) ? ev : ZQ;    // invalid -> zero row
    }
    uint4 u[8];
    #pragma unroll
    for (int j = 0; j < 8; j++)
        if (3 * j < deg) u[j] = h[(size_t)e[j] * 20 + off];   // wave-uniform skip
    #pragma unroll
    for (int j = 0; j < 8; j++) {
        if (3 * j < deg) {
            a[0] += __builtin_amdgcn_cvt_pk_f32_fp8(u[j].x, false);
            a[1] += __builtin_amdgcn_cvt_pk_f32_fp8(u[j].x, true);
            a[2] += __builtin_amdgcn_cvt_pk_f32_fp8(u[j].y, false);
            a[3] += __builtin_amdgcn_cvt_pk_f32_fp8(u[j].y, true);
            a[4] += __builtin_amdgcn_cvt_pk_f32_fp8(u[j].z, false);
            a[5] += __builtin_amdgcn_cvt_pk_f32_fp8(u[j].z, true);
            a[6] += __builtin_amdgcn_cvt_pk_f32_fp8(u[j].w, false);
            a[7] += __builtin_amdgcn_cvt_pk_f32_fp8(u[j].w, true);
        }
    }
    int k1g = k0 + degg;
    for (int k = k0 + 24 + s; k < k1g; k += 3) {   // rare: degree > 24 (~2%)
        int e0 = csr[k];
        uint4 u0 = h[(size_t)e0 * 20 + off];
        a[0] += __builtin_amdgcn_cvt_pk_f32_fp8(u0.x, false);
        a[1] += __builtin_amdgcn_cvt_pk_f32_fp8(u0.x, true);
        a[2] += __builtin_amdgcn_cvt_pk_f32_fp8(u0.y, false);
        a[3] += __builtin_amdgcn_cvt_pk_f32_fp8(u0.y, true);
        a[4] += __builtin_amdgcn_cvt_pk_f32_fp8(u0.z, false);
        a[5] += __builtin_amdgcn_cvt_pk_f32_fp8(u0.z, true);
        a[6] += __builtin_amdgcn_cvt_pk_f32_fp8(u0.w, false);
        a[7] += __builtin_amdgcn_cvt_pk_f32_fp8(u0.w, true);
    }
    float r[16];
    #pragma unroll
    for (int j = 0; j < 8; j++) {
        #pragma unroll
        for (int c = 0; c < 2; c++) {
            float v = a[j][c];
            r[2 * j + c] = v + __shfl(v, lane + 20, 64) + __shfl(v, lane + 40, 64);
        }
    }
    if (lane < 20) {
        float wi = inv_in[n];
        int d0 = __builtin_amdgcn_cvt_pk_fp8_f32(r[0] * wi, r[1] * wi, 0, false);
        d0 = __builtin_amdgcn_cvt_pk_fp8_f32(r[2] * wi, r[3] * wi, d0, true);
        int d1 = __builtin_amdgcn_cvt_pk_fp8_f32(r[4] * wi, r[5] * wi, 0, false);
        d1 = __builtin_amdgcn_cvt_pk_fp8_f32(r[6] * wi, r[7] * wi, d1, true);
        int d2 = __builtin_amdgcn_cvt_pk_fp8_f32(r[8] * wi, r[9] * wi, 0, false);
        d2 = __builtin_amdgcn_cvt_pk_fp8_f32(r[10] * wi, r[11] * wi, d2, true);
        int d3 = __builtin_amdgcn_cvt_pk_fp8_f32(r[12] * wi, r[13] * wi, 0, false);
        d3 = __builtin_amdgcn_cvt_pk_fp8_f32(r[14] * wi, r[15] * wi, d3, true);
        uint4 st; st.x = (unsigned)d0; st.y = (unsigned)d1; st.z = (unsigned)d2; st.w = (unsigned)d3;
        *(uint4*)(agg + (size_t)n * 320 + lane * 16) = st;
    }
}

// ------- fp8 MFMA GEMM: B fully LDS-resident, M-tile 256, 512 threads ----------
// B (320 x K fp8) staged ONCE per block; A double-buffered 16 KB/step.
// MODE 0: relu -> *inv_out -> fp8 rows (stride 320) to C8 (ghost rows ok)
// MODE 1: relu -> column max-pool -> atomicMax gpool; LAST block (done-counter)
//         runs the MLP head inline (pooled read via coherent atomicMax(p,0)).
template <int MODE, int K>
__global__ __launch_bounds__(512, 2) void k_gemm_mfma(
    const unsigned char* __restrict__ A,
    const unsigned char* __restrict__ Wt,
    const float* __restrict__ bias,
    const float* __restrict__ inv_out,
    unsigned char* __restrict__ C8, int* __restrict__ gpool, int M,
    int* __restrict__ done,
    const float* __restrict__ fW1, const float* __restrict__ fb1,
    const float* __restrict__ fW2, const float* __restrict__ fb2,
    const float* __restrict__ fW3, const float* __restrict__ fb3,
    float* __restrict__ out) {
    constexpr int BSZ = 320 * K;                     // full-B LDS bytes
    constexpr int SMSZ = (BSZ + 32768 > 81920) ? BSZ + 32768 : 81920;
    __shared__ char SM[SMSZ];                        // Bs | As dbuf; alias OUT/pmax
    __shared__ int lastflag;
    char* Bs = SM;
    char* As0 = SM + BSZ;                            // 2 x (256 rows x 64 B)
    int tid = threadIdx.x;
    int wv = tid >> 6, lane = tid & 63;
    int quad = lane >> 4, lrow = lane & 15;
    int bm = blockIdx.x * 256;

    f32x4 acc[2][19];
    #pragma unroll
    for (int r = 0; r < 2; r++)
        #pragma unroll
        for (int t = 0; t < 19; t++) acc[r][t] = (f32x4){0.f, 0.f, 0.f, 0.f};

    int swz = (lrow & 3) ^ (lrow >> 2);     // per-lane chunk-col xor term
    int hb = (quad & 1) * 8;                // 8B half within 16B chunk

    // prologue: stage full B (chunk-swizzled within each 64B segment) + A buf0
    constexpr int CPR = K / 16;             // chunks per B row
    constexpr int NBC = 320 * CPR;          // total B chunks
    #pragma unroll
    for (int j = 0; j < (NBC + 511) / 512; j++) {
        int c = j * 512 + tid;
        if (c < NBC) {                      // wave-uniform boundary
            int row = c / CPR, ws = c - row * CPR;
            int seg = ws >> 2, xc = ws & 3;
            int col = xc ^ (row & 3) ^ ((row >> 2) & 3);
            gload16(Wt + (size_t)row * K + seg * 64 + col * 16, Bs + c * 16);
        }
    }
    #pragma unroll
    for (int j = 0; j < 2; j++) {
        int c = j * 512 + tid;
        int row = c >> 2, xc = c & 3;
        int col = xc ^ (row & 3) ^ ((row >> 2) & 3);
        gload16(A + (size_t)(bm + row) * K + col * 16, As0 + c * 16);
    }
    __syncthreads();                        // implicit vmcnt(0): B + A0 ready

    constexpr int NT = K / 64;
    for (int t = 0; t < NT; t++) {
        const char* Asc = As0 + (t & 1) * 16384;
        if (t + 1 < NT) {
            char* Asn = As0 + ((t + 1) & 1) * 16384;
            int ktn = (t + 1) << 6;
            #pragma unroll
            for (int j = 0; j < 2; j++) {
                int c = j * 512 + tid;
                int row = c >> 2, xc = c & 3;
                int col = xc ^ (row & 3) ^ ((row >> 2) & 3);
                gload16(A + (size_t)(bm + row) * K + ktn + col * 16, Asn + c * 16);
            }
        }
        int kt = t << 6;
        #pragma unroll
        for (int sub = 0; sub < 2; sub++) {
            int c0 = sub * 2 + (quad >> 1);          // needed chunk col in segment
            int cx = (c0 ^ swz) * 16 + hb;           // swizzled byte offset
            int ra = wv * 32 + lrow;
            long long a0 = *(const long long*)(Asc + ra * 64 + cx);
            long long a1 = *(const long long*)(Asc + (ra + 16) * 64 + cx);
            #pragma unroll
            for (int u = 0; u < 19; u++) {
                long long b = *(const long long*)(Bs + (size_t)(u * 16 + lrow) * K + kt + cx);
                acc[0][u] = __builtin_amdgcn_mfma_f32_16x16x32_fp8_fp8(a0, b, acc[0][u], 0, 0, 0);
                acc[1][u] = __builtin_amdgcn_mfma_f32_16x16x32_fp8_fp8(a1, b, acc[1][u], 0, 0, 0);
            }
        }
        __syncthreads();             // drains vmcnt(0): next A buf ready; guards WAR
    }
    // epilogue: C/D layout col=lane&15, row=(lane>>4)*4+reg
    if (MODE == 0) {
        unsigned char* OUT = (unsigned char*)SM;   // 256 x 320 B = 81920 B
        if (tid < 256) *(uint4*)(OUT + tid * 320 + 304) = make_uint4(0u, 0u, 0u, 0u);
        #pragma unroll
        for (int t = 0; t < 19; t++) {
            int col = t * 16 + lrow;
            float bv = bias[col];
            #pragma unroll
            for (int r = 0; r < 2; r++) {
                int rl = wv * 32 + r * 16 + quad * 4;
                #pragma unroll
                for (int g = 0; g < 4; g++) {
                    int row = bm + rl + g;
                    float sc = inv_out[min(row, M - 1)];
                    float v = fmaxf(acc[r][t][g] + bv, 0.f) * sc;
                    int p = __builtin_amdgcn_cvt_pk_fp8_f32(v, v, 0, false);
                    OUT[(rl + g) * 320 + col] = (unsigned char)(p & 0xff);
                }
            }
        }
        __syncthreads();
        #pragma unroll
        for (int j = 0; j < 10; j++) {
            int c = j * 512 + tid;
            *(uint4*)(C8 + (size_t)bm * 320 + (size_t)c * 16) = *(const uint4*)(OUT + c * 16);
        }
    } else {
        int* pmax = (int*)SM;                      // alias (staging done)
        for (int i = tid; i < D_H; i += 512) pmax[i] = 0;
        __syncthreads();
        #pragma unroll
        for (int t = 0; t < 19; t++) {
            int col = t * 16 + lrow;
            float bv = bias[col];
            float m = 0.f;
            #pragma unroll
            for (int r = 0; r < 2; r++) {
                int rbase = bm + wv * 32 + r * 16 + quad * 4;
                #pragma unroll
                for (int g = 0; g < 4; g++) {
                    int row = rbase + g;
                    if (row < M) m = fmaxf(m, fmaxf(acc[r][t][g] + bv, 0.f));
                }
            }
            atomicMax(&pmax[col], __float_as_int(m));
        }
        __syncthreads();
        for (int i = tid; i < D_H; i += 512)
            atomicMax(&gpool[i], pmax[i]);
        // ----- last-block-done: run MLP head inline -----
        __syncthreads();                 // all this block's gpool atomics complete
        if (tid == 0) {
            __threadfence();             // make them visible before counting
            lastflag = (atomicAdd(done, 1) == (int)gridDim.x - 1);
        }
        __syncthreads();
        if (lastflag) {
            float* p  = (float*)SM;      // pmax no longer needed (block-local)
            float* z1 = p + 320;
            float* z2 = z1 + 128;
            for (int i = tid; i < D_H; i += 512)
                p[i] = __int_as_float(atomicMax(&gpool[i], 0));  // coherent read
            __syncthreads();
            if (tid < 128) {
                float acc0 = fb1[tid];
                for (int k = 0; k < D_H; k++) acc0 += p[k] * fW1[k * 128 + tid];
                z1[tid] = fmaxf(acc0, 0.f);
            }
            __syncthreads();
            if (tid < 64) {
                float acc0 = fb2[tid];
                for (int k = 0; k < 128; k++) acc0 += z1[k] * fW2[k * 64 + tid];
                z2[tid] = fmaxf(acc0, 0.f);
            }
            __syncthreads();
            if (tid == 0) {
                float acc0 = fb3[0];
                for (int k = 0; k < 64; k++) acc0 += z2[k] * fW3[k];
                out[0] = 1.f / (1.f + expf(-acc0));
            }
        }
    }
}

extern "C" void kernel_launch(void* const* d_in, const int* in_sizes, int n_in,
                              void* d_out, int out_size, void* d_ws, size_t ws_size,
                              hipStream_t stream) {
    const float* x1 = (const float*)d_in[0];
    const float* x2 = (const float*)d_in[1];
    const float* x3 = (const float*)d_in[2];
    const int* src1 = (const int*)d_in[3];
    const int* dst1 = (const int*)d_in[4];
    const int* src2 = (const int*)d_in[5];
    const int* dst2 = (const int*)d_in[6];
    const int* src3 = (const int*)d_in[7];
    const int* dst3 = (const int*)d_in[8];
    const float* W1 = (const float*)d_in[9];
    const float* b1 = (const float*)d_in[10];
    const float* W2 = (const float*)d_in[11];
    const float* b2 = (const float*)d_in[12];
    const float* W3 = (const float*)d_in[13];
    const float* b3 = (const float*)d_in[14];
    const float* fW1 = (const float*)d_in[15];
    const float* fb1 = (const float*)d_in[16];
    const float* fW2 = (const float*)d_in[17];
    const float* fb2 = (const float*)d_in[18];
    const float* fW3 = (const float*)d_in[19];
    const float* fb3 = (const float*)d_in[20];
    float* out = (float*)d_out;

    char* w = (char*)d_ws;
    unsigned* X8       = (unsigned*)w;      w += (size_t)(TOTN + 1) * 32 * 4;  // fp8 60001x128 (+zero row)
    unsigned char* Q8  = (unsigned char*)w; w += (size_t)(TOTN + 320) * 320;   // fp8 (+ghost/zero row)
    unsigned char* P8  = (unsigned char*)w; w += (size_t)(TOTN + 320) * 320;   // fp8 spmm out (+ghost)
    unsigned char* Wt1 = (unsigned char*)w; w += (size_t)320 * 128;            // padded rows
    unsigned char* Wt2 = (unsigned char*)w; w += (size_t)320 * 320;
    unsigned char* Wt3 = (unsigned char*)w; w += (size_t)320 * 320;
    w = (char*)(((size_t)w + 255) & ~(size_t)255);
    unsigned short* partial_in  = (unsigned short*)w; w += (size_t)NB * SLICES * NODES * 2;   // 4.8 MB
    unsigned short* partial_out = (unsigned short*)w; w += (size_t)NB * SLICES_O * NODES * 2; // 1.92 MB
    int* O         = (int*)w;    w += (size_t)NB * SLICES * NODES * 4;         // 9.6 MB
    float* inv_out = (float*)w;  w += (size_t)TOTN * 4;
    float* inv_in  = (float*)w;  w += (size_t)TOTN * 4;
    int* row_ptr   = (int*)w;    w += (size_t)TOTN * 4;
    int* rend      = (int*)w;    w += (size_t)TOTN * 4;
    int* csr       = (int*)w;    w += (size_t)(TOTE + 32) * 4;                 // +32 slack
    int* pooled    = (int*)w;    w += 320 * 4;
    int* gctr      = (int*)w;    w += 64;
    int* done      = gctr + 1;

    k_hist<<<dim3(NB * SLICES, 2), 1024, 0, stream>>>(src1, dst1, src2, dst2, src3, dst3,
                                                      partial_in, partial_out, gctr);
    k_degscan<<<SCAN_B, 1024, 0, stream>>>(partial_in, partial_out,
                                           inv_in, inv_out, row_ptr, rend, O, gctr);
    k_fillprep<<<FILLB + PACK1B + PREPW1B + 1, 1024, 0, stream>>>(
        src1, dst1, src2, dst2, src3, dst3, O, csr,
        (const float4*)x1, (const float4*)x2, (const float4*)x3, inv_out, X8,
        W1, W2, W3, Wt1, Wt2, Wt3,
        csr + TOTE, X8 + (size_t)ZX * 32, (unsigned*)(Q8 + (size_t)ZQ * 320), pooled, done);

    int ggrid = (TOTN + 255) / 256;  // 235

    // layer 1: X8(fp8*inv_out,128) -> SpMM -> P8(fp8,128B) -> GEMM(K=128) -> Q8
    k_spmm_l1<<<TOTN / 4, 256, 0, stream>>>((const uint2*)X8, P8, row_ptr, rend, csr, inv_in);
    k_gemm_mfma<0, 128><<<ggrid, 512, 0, stream>>>(P8, Wt1, b1, inv_out,
                                                   Q8, nullptr, TOTN, nullptr,
                                                   nullptr, nullptr, nullptr, nullptr,
                                                   nullptr, nullptr, nullptr);
    // layer 2
    k_spmm_big<<<TOTN / 4, 256, 0, stream>>>((const uint4*)Q8, P8, row_ptr, rend, csr, inv_in);
    k_gemm_mfma<0, 320><<<ggrid, 512, 0, stream>>>(P8, Wt2, b2, inv_out,
                                                   Q8, nullptr, TOTN, nullptr,
                                                   nullptr, nullptr, nullptr, nullptr,
                                                   nullptr, nullptr, nullptr);
    // layer 3: GEMM fused with column max-pool + inline MLP head (last block)
    k_spmm_big<<<TOTN / 4, 256, 0, stream>>>((const uint4*)Q8, P8, row_ptr, rend, csr, inv_in);
    k_gemm_mfma<1, 320><<<ggrid, 512, 0, stream>>>(P8, Wt3, b3, nullptr,
                                                   nullptr, pooled, TOTN, done,
                                                   fW1, fb1, fW2, fb2, fW3, fb3, out);
}

// Round 12
// 296.426 us; speedup vs baseline: 1.0173x; 1.0173x over previous
//
#include <hip/hip_runtime.h>
#include <hip/hip_bf16.h>
#include <math.h>

#define NODES 20000
#define EDGES 320000
#define NB 3
#define TOTN (NODES * NB)   // 60000
#define TOTE (EDGES * NB)   // 960000
#define D_IN 128
#define D_H 304
#define SCAN_B 59           // ceil(60000/1024)
#define SLICES 40
#define SLICE_E (EDGES / SLICES)   // 8000
#define ZX TOTN             // zero row index in X8 (row 60000)
#define ZQ (TOTN + 192)     // zero row index in Q8/P8 (row 60192, above GEMM ghost rows <=60159)
#define FILLB 120           // fill blocks in merged kernel
#define PACK1B 1875         // pack blocks (exact: 1920000/1024)
#define PREPW1B 240         // prepw blocks (exact: 245760/1024)

typedef __attribute__((ext_vector_type(4))) float f32x4;
typedef __attribute__((ext_vector_type(2))) float f32x2;

// async global->LDS, 16 B per lane; LDS dst must be wave-uniform base + lane*16
__device__ __forceinline__ void gload16(const void* g, void* l) {
    __builtin_amdgcn_global_load_lds(
        (const __attribute__((address_space(1))) unsigned*)g,
        (__attribute__((address_space(3))) unsigned*)l, 16, 0, 0);
}

// ------- per-(graph,slice) LDS histograms, packed 2 nodes/word (16b counts) -----
__global__ __launch_bounds__(1024, 1) void k_hist(
    const int* __restrict__ s1, const int* __restrict__ d1,
    const int* __restrict__ s2, const int* __restrict__ d2,
    const int* __restrict__ s3, const int* __restrict__ d3,
    unsigned short* __restrict__ partial_in, unsigned short* __restrict__ partial_out,
    int* __restrict__ gctr) {
    __shared__ unsigned hist[NODES / 2];   // 40 KB
    if (blockIdx.x == 0 && blockIdx.y == 0 && threadIdx.x == 0) *gctr = 0;
    int g = blockIdx.x / SLICES, s = blockIdx.x % SLICES;
    bool isOut = (blockIdx.y == 1);
    const int* ep;
    if (isOut) ep = (g == 0) ? s1 : ((g == 1) ? s2 : s3);
    else       ep = (g == 0) ? d1 : ((g == 1) ? d2 : d3);
    ep += s * SLICE_E;
    for (int i = threadIdx.x; i < NODES / 2; i += 1024) hist[i] = 0;
    __syncthreads();
    const int4* ep4 = (const int4*)ep;
    for (int i = threadIdx.x; i < SLICE_E / 4; i += 1024) {
        int4 v = ep4[i];
        atomicAdd(&hist[v.x >> 1], 1u << ((v.x & 1) << 4));
        atomicAdd(&hist[v.y >> 1], 1u << ((v.y & 1) << 4));
        atomicAdd(&hist[v.z >> 1], 1u << ((v.z & 1) << 4));
        atomicAdd(&hist[v.w >> 1], 1u << ((v.w & 1) << 4));
    }
    __syncthreads();
    unsigned* po = (unsigned*)((isOut ? partial_out : partial_in) + (size_t)blockIdx.x * NODES);
    for (int i = threadIdx.x; i < NODES / 2; i += 1024) po[i] = hist[i];
}

// ------- degrees + inv factors + row_ptr (atomic block base) + O slice bases ---
// partial_in column register-cached (single pass feeds both ci sum and O bases).
__global__ void k_degscan(const unsigned short* __restrict__ partial_in,
                          const unsigned short* __restrict__ partial_out,
                          float* __restrict__ inv_in, float* __restrict__ inv_out,
                          int* __restrict__ row_ptr, int* __restrict__ rend,
                          int* __restrict__ O, int* __restrict__ gctr) {
    __shared__ int wsum[16];
    __shared__ int sbase;
    int b = blockIdx.x, t = threadIdx.x;
    int i = b * 1024 + t;
    int lane = t & 63, wid = t >> 6;
    int v = 0;
    int g = 0, ln = 0;
    int pc[SLICES];
    if (i < TOTN) {
        g = i / NODES; ln = i - g * NODES;
        const unsigned short* pi = partial_in + (size_t)g * SLICES * NODES + ln;
        const unsigned short* po = partial_out + (size_t)g * SLICES * NODES + ln;
        int ci = 0, co = 0;
        #pragma unroll
        for (int s = 0; s < SLICES; s++) { pc[s] = pi[s * NODES]; ci += pc[s]; co += po[s * NODES]; }
        v = ci;
        inv_in[i]  = 1.0f / sqrtf((float)max(ci, 1));
        inv_out[i] = 1.0f / sqrtf((float)max(co, 1));
    }
    int sv = v;
    #pragma unroll
    for (int o = 1; o < 64; o <<= 1) {
        int u = __shfl_up(sv, o, 64);
        if (lane >= o) sv += u;
    }
    if (lane == 63) wsum[wid] = sv;
    __syncthreads();
    if (t < 16) {
        int w = wsum[t];
        #pragma unroll
        for (int o = 1; o < 16; o <<= 1) {
            int u = __shfl_up(w, o, 16);
            if (t >= o) w += u;
        }
        wsum[t] = w;
    }
    __syncthreads();
    if (t == 0) sbase = atomicAdd(gctr, wsum[15]);
    __syncthreads();
    int wbase = (wid > 0) ? wsum[wid - 1] : 0;
    if (i < TOTN) {
        int rp = sbase + wbase + sv - v;
        row_ptr[i] = rp;
        rend[i] = rp + v;
        int* on = O + (size_t)g * SLICES * NODES + ln;
        int run = rp;
        #pragma unroll
        for (int s = 0; s < SLICES; s++) {
            on[s * NODES] = run;
            run += pc[s];
        }
    }
}

// ------- merged: CSR fill (LDS cursors) | pack x->fp8 | W prep | zero jobs -----
__global__ __launch_bounds__(1024, 1) void k_fillprep(
    const int* __restrict__ s1, const int* __restrict__ d1,
    const int* __restrict__ s2, const int* __restrict__ d2,
    const int* __restrict__ s3, const int* __restrict__ d3,
    const int* __restrict__ O, int* __restrict__ csr,
    const float4* __restrict__ x1, const float4* __restrict__ x2,
    const float4* __restrict__ x3, const float* __restrict__ inv_out,
    unsigned* __restrict__ q,
    const float* __restrict__ W1, const float* __restrict__ W2,
    const float* __restrict__ W3,
    unsigned char* __restrict__ Wt1, unsigned char* __restrict__ Wt2,
    unsigned char* __restrict__ Wt3,
    int* __restrict__ csr_slack, unsigned* __restrict__ x8z,
    unsigned* __restrict__ q8z, int* __restrict__ pooled) {
    __shared__ int cur[NODES];   // 80 KB (used by fill-role blocks only)
    int b = blockIdx.x;
    if (b < FILLB) {
        int g = b / SLICES, s = b % SLICES;
        const int* sp = (g == 0) ? s1 : ((g == 1) ? s2 : s3);
        const int* dp = (g == 0) ? d1 : ((g == 1) ? d2 : d3);
        sp += s * SLICE_E; dp += s * SLICE_E;
        const int* on = O + (size_t)b * NODES;
        for (int i = threadIdx.x; i < NODES; i += 1024) cur[i] = on[i];
        __syncthreads();
        int base = g * NODES;
        const int4* sp4 = (const int4*)sp;
        const int4* dp4 = (const int4*)dp;
        for (int i = threadIdx.x; i < SLICE_E / 4; i += 1024) {
            int4 dv = dp4[i];
            int4 sv = sp4[i];
            int p0 = atomicAdd(&cur[dv.x], 1); csr[p0] = sv.x + base;
            int p1 = atomicAdd(&cur[dv.y], 1); csr[p1] = sv.y + base;
            int p2 = atomicAdd(&cur[dv.z], 1); csr[p2] = sv.z + base;
            int p3 = atomicAdd(&cur[dv.w], 1); csr[p3] = sv.w + base;
        }
    } else if (b < FILLB + PACK1B) {
        const int per = NODES * D_IN / 4;  // float4s per graph (32 per row)
        int i = (b - FILLB) * 1024 + threadIdx.x;   // covers 3*per exactly
        const float4* s; int j;
        if (i < per)          { s = x1; j = i; }
        else if (i < 2 * per) { s = x2; j = i - per; }
        else                  { s = x3; j = i - 2 * per; }
        float4 v = s[j];
        float sc = inv_out[i >> 5];   // 32 dwords per row, global node id
        int p = __builtin_amdgcn_cvt_pk_fp8_f32(v.x * sc, v.y * sc, 0, false);
        p = __builtin_amdgcn_cvt_pk_fp8_f32(v.z * sc, v.w * sc, p, true);
        q[i] = (unsigned)p;
    } else if (b < FILLB + PACK1B + PREPW1B) {
        // Wt padded to 320 rows (rows 304-319 zero) for uniform GEMM B staging.
        const int N1 = 320 * 128, N2 = 320 * 320;
        int id = (b - FILLB - PACK1B) * 1024 + threadIdx.x;
        const float* W; unsigned char* Wt; int K, Kpad, lid;
        if (id < N1)                { W = W1; Wt = Wt1; K = 128; Kpad = 128; lid = id; }
        else if (id < N1 + N2)      { W = W2; Wt = Wt2; K = 304; Kpad = 320; lid = id - N1; }
        else                        { W = W3; Wt = Wt3; K = 304; Kpad = 320; lid = id - N1 - N2; }
        int n = lid / Kpad, k = lid - n * Kpad;
        unsigned char v = 0;
        if (k < K && n < D_H) {
            float w = W[k * D_H + n];
            v = (unsigned char)(__builtin_amdgcn_cvt_pk_fp8_f32(w, w, 0, false) & 0xff);
        }
        Wt[lid] = v;
    } else {
        int ex = threadIdx.x;
        if (ex < 32) csr_slack[ex] = 0;            // csr over-read slack
        else if (ex < 64) x8z[ex - 32] = 0;        // X8 zero row (128 B)
        else if (ex < 144) q8z[ex - 64] = 0;       // Q8 zero row (320 B)
        else if (ex < 464) pooled[ex - 144] = 0;   // pooled accumulator
    }
}

// ------- SpMM layer 1: straight-line predicated gather, 32 edges deep ---------
// (proven structure: 48 VGPR, no spill. One node/wave, 4 subgroups x 16 lanes)
__global__ void k_spmm_l1(const uint2* __restrict__ h, unsigned char* __restrict__ agg,
                          const int* __restrict__ row_ptr, const int* __restrict__ rend,
                          const int* __restrict__ csr,
                          const float* __restrict__ inv_in) {
    int n = blockIdx.x * 4 + (threadIdx.x >> 6);
    int lane = threadIdx.x & 63;
    int s = lane >> 4;          // edge subgroup 0..3
    int off = lane & 15;        // uint2 offset within row
    f32x2 a[4];
    #pragma unroll
    for (int j = 0; j < 4; j++) a[j] = (f32x2){0.f, 0.f};
    int k0 = row_ptr[n], k1 = rend[n];
    int deg = k1 - k0;
    const int* cp = csr + k0 + s;
    int e[8];
    #pragma unroll
    for (int j = 0; j < 8; j++) {
        int ev = cp[4 * j];                     // imm-offset load; slack-safe
        e[j] = (s + 4 * j < deg) ? ev : ZX;     // invalid -> zero row
    }
    uint2 u[8];
    #pragma unroll
    for (int j = 0; j < 8; j++)
        if (4 * j < deg) u[j] = h[(size_t)e[j] * 16 + off];   // wave-uniform skip
    #pragma unroll
    for (int j = 0; j < 8; j++) {
        if (4 * j < deg) {
            a[0] += __builtin_amdgcn_cvt_pk_f32_fp8(u[j].x, false);
            a[1] += __builtin_amdgcn_cvt_pk_f32_fp8(u[j].x, true);
            a[2] += __builtin_amdgcn_cvt_pk_f32_fp8(u[j].y, false);
            a[3] += __builtin_amdgcn_cvt_pk_f32_fp8(u[j].y, true);
        }
    }
    for (int k = k0 + 32 + s; k < k1; k += 4) {    // rare: degree > 32
        int e0 = csr[k];
        uint2 u0 = h[(size_t)e0 * 16 + off];
        a[0] += __builtin_amdgcn_cvt_pk_f32_fp8(u0.x, false);
        a[1] += __builtin_amdgcn_cvt_pk_f32_fp8(u0.x, true);
        a[2] += __builtin_amdgcn_cvt_pk_f32_fp8(u0.y, false);
        a[3] += __builtin_amdgcn_cvt_pk_f32_fp8(u0.y, true);
    }
    float r[8];
    #pragma unroll
    for (int j = 0; j < 4; j++) {
        #pragma unroll
        for (int c = 0; c < 2; c++) {
            float v = a[j][c];
            r[2 * j + c] = v + __shfl(v, lane + 16, 64)
                             + __shfl(v, lane + 32, 64)
                             + __shfl(v, lane + 48, 64);
        }
    }
    if (lane < 16) {
        float wi = inv_in[n];
        int d0 = __builtin_amdgcn_cvt_pk_fp8_f32(r[0] * wi, r[1] * wi, 0, false);
        d0 = __builtin_amdgcn_cvt_pk_fp8_f32(r[2] * wi, r[3] * wi, d0, true);
        int d1 = __builtin_amdgcn_cvt_pk_fp8_f32(r[4] * wi, r[5] * wi, 0, false);
        d1 = __builtin_amdgcn_cvt_pk_fp8_f32(r[6] * wi, r[7] * wi, d1, true);
        uint2 st; st.x = (unsigned)d0; st.y = (unsigned)d1;
        *(uint2*)(agg + (size_t)n * 128 + lane * 8) = st;
    }
}

// ------- SpMM layers 2/3: straight-line predicated gather, 24 edges deep ------
__global__ void k_spmm_big(const uint4* __restrict__ h, unsigned char* __restrict__ agg,
                           const int* __restrict__ row_ptr, const int* __restrict__ rend,
                           const int* __restrict__ csr,
                           const float* __restrict__ inv_in) {
    int n = blockIdx.x * 4 + (threadIdx.x >> 6);
    int lane = threadIdx.x & 63;
    int s = lane / 20;          // 0..2 (lanes 60-63: s=3, masked)
    int off = lane % 20;
    f32x2 a[8];
    #pragma unroll
    for (int j = 0; j < 8; j++) a[j] = (f32x2){0.f, 0.f};
    int k0 = row_ptr[n], k1 = rend[n];
    int deg = k1 - k0;
    int degg = (s < 3) ? deg : 0;         // s==3 lanes always invalid
    const int* cp = csr + k0 + s;
    int e[8];
    #pragma unroll
    for (int j = 0; j < 8; j++) {
        int ev = cp[3 * j];                     // imm-offset load; slack-safe
        e[j] = (s + 3 * j < degg) ? ev : ZQ;    // invalid -> zero row
    }
    uint4 u[8];
    #pragma unroll
    for (int j = 0; j < 8; j++)
        if (3 * j < deg) u[j] = h[(size_t)e[j] * 20 + off];   // wave-uniform skip
    #pragma unroll
    for (int j = 0; j < 8; j++) {
        if (3 * j < deg) {
            a[0] += __builtin_amdgcn_cvt_pk_f32_fp8(u[j].x, false);
            a[1] += __builtin_amdgcn_cvt_pk_f32_fp8(u[j].x, true);
            a[2] += __builtin_amdgcn_cvt_pk_f32_fp8(u[j].y, false);
            a[3] += __builtin_amdgcn_cvt_pk_f32_fp8(u[j].y, true);
            a[4] += __builtin_amdgcn_cvt_pk_f32_fp8(u[j].z, false);
            a[5] += __builtin_amdgcn_cvt_pk_f32_fp8(u[j].z, true);
            a[6] += __builtin_amdgcn_cvt_pk_f32_fp8(u[j].w, false);
            a[7] += __builtin_amdgcn_cvt_pk_f32_fp8(u[j].w, true);
        }
    }
    int k1g = k0 + degg;
    for (int k = k0 + 24 + s; k < k1g; k += 3) {   // rare: degree > 24 (~2%)
        int e0 = csr[k];
        uint4 u0 = h[(size_t)e0 * 20 + off];
        a[0] += __builtin_amdgcn_cvt_pk_f32_fp8(u0.x, false);
        a[1] += __builtin_amdgcn_cvt_pk_f32_fp8(u0.x, true);
        a[2] += __builtin_amdgcn_cvt_pk_f32_fp8(u0.y, false);
        a[3] += __builtin_amdgcn_cvt_pk_f32_fp8(u0.y, true);
        a[4] += __builtin_amdgcn_cvt_pk_f32_fp8(u0.z, false);
        a[5] += __builtin_amdgcn_cvt_pk_f32_fp8(u0.z, true);
        a[6] += __builtin_amdgcn_cvt_pk_f32_fp8(u0.w, false);
        a[7] += __builtin_amdgcn_cvt_pk_f32_fp8(u0.w, true);
    }
    float r[16];
    #pragma unroll
    for (int j = 0; j < 8; j++) {
        #pragma unroll
        for (int c = 0; c < 2; c++) {
            float v = a[j][c];
            r[2 * j + c] = v + __shfl(v, lane + 20, 64) + __shfl(v, lane + 40, 64);
        }
    }
    if (lane < 20) {
        float wi = inv_in[n];
        int d0 = __builtin_amdgcn_cvt_pk_fp8_f32(r[0] * wi, r[1] * wi, 0, false);
        d0 = __builtin_amdgcn_cvt_pk_fp8_f32(r[2] * wi, r[3] * wi, d0, true);
        int d1 = __builtin_amdgcn_cvt_pk_fp8_f32(r[4] * wi, r[5] * wi, 0, false);
        d1 = __builtin_amdgcn_cvt_pk_fp8_f32(r[6] * wi, r[7] * wi, d1, true);
        int d2 = __builtin_amdgcn_cvt_pk_fp8_f32(r[8] * wi, r[9] * wi, 0, false);
        d2 = __builtin_amdgcn_cvt_pk_fp8_f32(r[10] * wi, r[11] * wi, d2, true);
        int d3 = __builtin_amdgcn_cvt_pk_fp8_f32(r[12] * wi, r[13] * wi, 0, false);
        d3 = __builtin_amdgcn_cvt_pk_fp8_f32(r[14] * wi, r[15] * wi, d3, true);
        uint4 st; st.x = (unsigned)d0; st.y = (unsigned)d1; st.z = (unsigned)d2; st.w = (unsigned)d3;
        *(uint4*)(agg + (size_t)n * 320 + lane * 16) = st;
    }
}

// ------- fp8 MFMA GEMM: B fully LDS-resident, M-tile 256, 512 threads ----------
// B (320 x K fp8) staged ONCE per block; A double-buffered 16 KB/step.
// MODE 0: relu -> *inv_out -> fp8 rows (stride 320) to C8 (ghost rows ok)
// MODE 1: relu -> column max-pool -> atomicMax gpool
template <int MODE, int K>
__global__ __launch_bounds__(512, 2) void k_gemm_mfma(
    const unsigned char* __restrict__ A,
    const unsigned char* __restrict__ Wt,
    const float* __restrict__ bias,
    const float* __restrict__ inv_out,
    unsigned char* __restrict__ C8, int* __restrict__ gpool, int M) {
    constexpr int BSZ = 320 * K;                     // full-B LDS bytes
    constexpr int SMSZ = (BSZ + 32768 > 81920) ? BSZ + 32768 : 81920;
    __shared__ char SM[SMSZ];                        // Bs | As dbuf; alias OUT/pmax
    char* Bs = SM;
    char* As0 = SM + BSZ;                            // 2 x (256 rows x 64 B)
    int tid = threadIdx.x;
    int wv = tid >> 6, lane = tid & 63;
    int quad = lane >> 4, lrow = lane & 15;
    int bm = blockIdx.x * 256;

    f32x4 acc[2][19];
    #pragma unroll
    for (int r = 0; r < 2; r++)
        #pragma unroll
        for (int t = 0; t < 19; t++) acc[r][t] = (f32x4){0.f, 0.f, 0.f, 0.f};

    int swz = (lrow & 3) ^ (lrow >> 2);     // per-lane chunk-col xor term
    int hb = (quad & 1) * 8;                // 8B half within 16B chunk

    // prologue: stage full B (chunk-swizzled within each 64B segment) + A buf0
    constexpr int CPR = K / 16;             // chunks per B row
    constexpr int NBC = 320 * CPR;          // total B chunks
    #pragma unroll
    for (int j = 0; j < (NBC + 511) / 512; j++) {
        int c = j * 512 + tid;
        if (c < NBC) {                      // wave-uniform boundary
            int row = c / CPR, ws = c - row * CPR;
            int seg = ws >> 2, xc = ws & 3;
            int col = xc ^ (row & 3) ^ ((row >> 2) & 3);
            gload16(Wt + (size_t)row * K + seg * 64 + col * 16, Bs + c * 16);
        }
    }
    #pragma unroll
    for (int j = 0; j < 2; j++) {
        int c = j * 512 + tid;
        int row = c >> 2, xc = c & 3;
        int col = xc ^ (row & 3) ^ ((row >> 2) & 3);
        gload16(A + (size_t)(bm + row) * K + col * 16, As0 + c * 16);
    }
    __syncthreads();                        // implicit vmcnt(0): B + A0 ready

    constexpr int NT = K / 64;
    for (int t = 0; t < NT; t++) {
        const char* Asc = As0 + (t & 1) * 16384;
        if (t + 1 < NT) {
            char* Asn = As0 + ((t + 1) & 1) * 16384;
            int ktn = (t + 1) << 6;
            #pragma unroll
            for (int j = 0; j < 2; j++) {
                int c = j * 512 + tid;
                int row = c >> 2, xc = c & 3;
                int col = xc ^ (row & 3) ^ ((row >> 2) & 3);
                gload16(A + (size_t)(bm + row) * K + ktn + col * 16, Asn + c * 16);
            }
        }
        int kt = t << 6;
        #pragma unroll
        for (int sub = 0; sub < 2; sub++) {
            int c0 = sub * 2 + (quad >> 1);          // needed chunk col in segment
            int cx = (c0 ^ swz) * 16 + hb;           // swizzled byte offset
            int ra = wv * 32 + lrow;
            long long a0 = *(const long long*)(Asc + ra * 64 + cx);
            long long a1 = *(const long long*)(Asc + (ra + 16) * 64 + cx);
            #pragma unroll
            for (int u = 0; u < 19; u++) {
                long long b = *(const long long*)(Bs + (size_t)(u * 16 + lrow) * K + kt + cx);
                acc[0][u] = __builtin_amdgcn_mfma_f32_16x16x32_fp8_fp8(a0, b, acc[0][u], 0, 0, 0);
                acc[1][u] = __builtin_amdgcn_mfma_f32_16x16x32_fp8_fp8(a1, b, acc[1][u], 0, 0, 0);
            }
        }
        __syncthreads();             // drains vmcnt(0): next A buf ready; guards WAR
    }
    // epilogue: C/D layout col=lane&15, row=(lane>>4)*4+reg
    if (MODE == 0) {
        unsigned char* OUT = (unsigned char*)SM;   // 256 x 320 B = 81920 B
        if (tid < 256) *(uint4*)(OUT + tid * 320 + 304) = make_uint4(0u, 0u, 0u, 0u);
        #pragma unroll
        for (int t = 0; t < 19; t++) {
            int col = t * 16 + lrow;
            float bv = bias[col];
            #pragma unroll
            for (int r = 0; r < 2; r++) {
                int rl = wv * 32 + r * 16 + quad * 4;
                #pragma unroll
                for (int g = 0; g < 4; g++) {
                    int row = bm + rl + g;
                    float sc = inv_out[min(row, M - 1)];
                    float v = fmaxf(acc[r][t][g] + bv, 0.f) * sc;
                    int p = __builtin_amdgcn_cvt_pk_fp8_f32(v, v, 0, false);
                    OUT[(rl + g) * 320 + col] = (unsigned char)(p & 0xff);
                }
            }
        }
        __syncthreads();
        #pragma unroll
        for (int j = 0; j < 10; j++) {
            int c = j * 512 + tid;
            *(uint4*)(C8 + (size_t)bm * 320 + (size_t)c * 16) = *(const uint4*)(OUT + c * 16);
        }
    } else {
        int* pmax = (int*)SM;                      // alias (staging done)
        for (int i = tid; i < D_H; i += 512) pmax[i] = 0;
        __syncthreads();
        #pragma unroll
        for (int t = 0; t < 19; t++) {
            int col = t * 16 + lrow;
            float bv = bias[col];
            float m = 0.f;
            #pragma unroll
            for (int r = 0; r < 2; r++) {
                int rbase = bm + wv * 32 + r * 16 + quad * 4;
                #pragma unroll
                for (int g = 0; g < 4; g++) {
                    int row = rbase + g;
                    if (row < M) m = fmaxf(m, fmaxf(acc[r][t][g] + bv, 0.f));
                }
            }
            atomicMax(&pmax[col], __float_as_int(m));
        }
        __syncthreads();
        for (int i = tid; i < D_H; i += 512)
            atomicMax(&gpool[i], pmax[i]);
    }
}

// ---------------- MLP head: 304 -> 128 -> 64 -> 1, sigmoid ----------------
__global__ void k_mlp(const int* __restrict__ pooled_i,
                      const float* __restrict__ fW1, const float* __restrict__ fb1,
                      const float* __restrict__ fW2, const float* __restrict__ fb2,
                      const float* __restrict__ fW3, const float* __restrict__ fb3,
                      float* __restrict__ out) {
    __shared__ float p[D_H];
    __shared__ float z1[128];
    __shared__ float z2[64];
    int t = threadIdx.x;  // 320
    if (t < D_H) p[t] = __int_as_float(pooled_i[t]);
    __syncthreads();
    if (t < 128) {
        float acc = fb1[t];
        for (int k = 0; k < D_H; k++) acc += p[k] * fW1[k * 128 + t];
        z1[t] = fmaxf(acc, 0.f);
    }
    __syncthreads();
    if (t < 64) {
        float acc = fb2[t];
        for (int k = 0; k < 128; k++) acc += z1[k] * fW2[k * 64 + t];
        z2[t] = fmaxf(acc, 0.f);
    }
    __syncthreads();
    if (t == 0) {
        float acc = fb3[0];
        for (int k = 0; k < 64; k++) acc += z2[k] * fW3[k];
        out[0] = 1.f / (1.f + expf(-acc));
    }
}

extern "C" void kernel_launch(void* const* d_in, const int* in_sizes, int n_in,
                              void* d_out, int out_size, void* d_ws, size_t ws_size,
                              hipStream_t stream) {
    const float* x1 = (const float*)d_in[0];
    const float* x2 = (const float*)d_in[1];
    const float* x3 = (const float*)d_in[2];
    const int* src1 = (const int*)d_in[3];
    const int* dst1 = (const int*)d_in[4];
    const int* src2 = (const int*)d_in[5];
    const int* dst2 = (const int*)d_in[6];
    const int* src3 = (const int*)d_in[7];
    const int* dst3 = (const int*)d_in[8];
    const float* W1 = (const float*)d_in[9];
    const float* b1 = (const float*)d_in[10];
    const float* W2 = (const float*)d_in[11];
    const float* b2 = (const float*)d_in[12];
    const float* W3 = (const float*)d_in[13];
    const float* b3 = (const float*)d_in[14];
    const float* fW1 = (const float*)d_in[15];
    const float* fb1 = (const float*)d_in[16];
    const float* fW2 = (const float*)d_in[17];
    const float* fb2 = (const float*)d_in[18];
    const float* fW3 = (const float*)d_in[19];
    const float* fb3 = (const float*)d_in[20];
    float* out = (float*)d_out;

    char* w = (char*)d_ws;
    unsigned* X8       = (unsigned*)w;      w += (size_t)(TOTN + 1) * 32 * 4;  // fp8 60001x128 (+zero row)
    unsigned char* Q8  = (unsigned char*)w; w += (size_t)(TOTN + 320) * 320;   // fp8 (+ghost/zero row)
    unsigned char* P8  = (unsigned char*)w; w += (size_t)(TOTN + 320) * 320;   // fp8 spmm out (+ghost)
    unsigned char* Wt1 = (unsigned char*)w; w += (size_t)320 * 128;            // padded rows
    unsigned char* Wt2 = (unsigned char*)w; w += (size_t)320 * 320;
    unsigned char* Wt3 = (unsigned char*)w; w += (size_t)320 * 320;
    w = (char*)(((size_t)w + 255) & ~(size_t)255);
    unsigned short* partial_in  = (unsigned short*)w; w += (size_t)NB * SLICES * NODES * 2; // 4.8 MB
    unsigned short* partial_out = (unsigned short*)w; w += (size_t)NB * SLICES * NODES * 2;
    int* O         = (int*)w;    w += (size_t)NB * SLICES * NODES * 4;         // 9.6 MB
    float* inv_out = (float*)w;  w += (size_t)TOTN * 4;
    float* inv_in  = (float*)w;  w += (size_t)TOTN * 4;
    int* row_ptr   = (int*)w;    w += (size_t)TOTN * 4;
    int* rend      = (int*)w;    w += (size_t)TOTN * 4;
    int* csr       = (int*)w;    w += (size_t)(TOTE + 32) * 4;                 // +32 slack
    int* pooled    = (int*)w;    w += 320 * 4;
    int* gctr      = (int*)w;    w += 64;

    k_hist<<<dim3(NB * SLICES, 2), 1024, 0, stream>>>(src1, dst1, src2, dst2, src3, dst3,
                                                      partial_in, partial_out, gctr);
    k_degscan<<<SCAN_B, 1024, 0, stream>>>(partial_in, partial_out,
                                           inv_in, inv_out, row_ptr, rend, O, gctr);
    k_fillprep<<<FILLB + PACK1B + PREPW1B + 1, 1024, 0, stream>>>(
        src1, dst1, src2, dst2, src3, dst3, O, csr,
        (const float4*)x1, (const float4*)x2, (const float4*)x3, inv_out, X8,
        W1, W2, W3, Wt1, Wt2, Wt3,
        csr + TOTE, X8 + (size_t)ZX * 32, (unsigned*)(Q8 + (size_t)ZQ * 320), pooled);

    int ggrid = (TOTN + 255) / 256;  // 235

    // layer 1: X8(fp8*inv_out,128) -> SpMM -> P8(fp8,128B) -> GEMM(K=128) -> Q8
    k_spmm_l1<<<TOTN / 4, 256, 0, stream>>>((const uint2*)X8, P8, row_ptr, rend, csr, inv_in);
    k_gemm_mfma<0, 128><<<ggrid, 512, 0, stream>>>(P8, Wt1, b1, inv_out,
                                                   Q8, nullptr, TOTN);
    // layer 2
    k_spmm_big<<<TOTN / 4, 256, 0, stream>>>((const uint4*)Q8, P8, row_ptr, rend, csr, inv_in);
    k_gemm_mfma<0, 320><<<ggrid, 512, 0, stream>>>(P8, Wt2, b2, inv_out,
                                                   Q8, nullptr, TOTN);
    // layer 3: GEMM fused with column max-pool (no h3 materialization)
    k_spmm_big<<<TOTN / 4, 256, 0, stream>>>((const uint4*)Q8, P8, row_ptr, rend, csr, inv_in);
    k_gemm_mfma<1, 320><<<ggrid, 512, 0, stream>>>(P8, Wt3, b3, nullptr,
                                                   nullptr, pooled, TOTN);

    k_mlp<<<1, 320, 0, stream>>>(pooled, fW1, fb1, fW2, fb2, fW3, fb3, out);
}